// Round 5
// baseline (756.072 us; speedup 1.0000x reference)
//
#include <hip/hip_runtime.h>

typedef __attribute__((ext_vector_type(8))) short bf16x8;
typedef __attribute__((ext_vector_type(4))) float f32x4;
typedef __attribute__((ext_vector_type(4))) unsigned int u32x4;

#define DEVINL __device__ __forceinline__

DEVINL unsigned short f2bf(float f){
  unsigned int u = __float_as_uint(f);
  unsigned int r = (u + 0x7FFFu + ((u >> 16) & 1u)) >> 16;
  return (unsigned short)r;
}
DEVINL float bf2f(unsigned short h){ return __uint_as_float(((unsigned int)h) << 16); }
DEVINL unsigned int fkey(float f){
  unsigned int u = __float_as_uint(f);
  return (u & 0x80000000u) ? ~u : (u | 0x80000000u);
}
DEVINL float fkeyinv(unsigned int k){
  unsigned int u = (k & 0x80000000u) ? (k & 0x7FFFFFFFu) : ~k;
  return __uint_as_float(u);
}
DEVINL unsigned int cvtpk(float lo, float hi){
  unsigned int r;
  asm("v_cvt_pk_bf16_f32 %0, %1, %2" : "=v"(r) : "v"(lo), "v"(hi));
  return r;
}

// ---------------- prep: f32 -> bf16 hi (+ optional lo residual) ----------------
__global__ void prep_split_kernel(const float* __restrict__ src,
                                  unsigned short* __restrict__ hi,
                                  unsigned short* __restrict__ lo, int n){
  int i = blockIdx.x * 256 + threadIdx.x;
  if (i >= n) return;
  float f = src[i];
  unsigned short h = f2bf(f);
  hi[i] = h;
  if (lo) lo[i] = f2bf(f - bf2f(h));
}

// ---------------- GEMM: C[m,n] = sum_k A[m,k]*B[n,k] + bias, 128x128 tile ----------------
template<bool SPLIT, int EPI>
__global__ __launch_bounds__(256) void gemm_kernel(
    const unsigned short* __restrict__ Ah, const unsigned short* __restrict__ Al,
    const unsigned short* __restrict__ Bh, const unsigned short* __restrict__ Bl,
    const float* __restrict__ bias0, const float* __restrict__ bias1, const float* __restrict__ bias2,
    unsigned short* __restrict__ qh, unsigned short* __restrict__ ql,
    unsigned short* __restrict__ kh, unsigned short* __restrict__ kl,
    unsigned short* __restrict__ vT, float* __restrict__ outf)
{
  const int K = 1024;
  __shared__ __align__(16) unsigned short sAh[128*40];
  __shared__ __align__(16) unsigned short sBh[128*40];
  __shared__ __align__(16) unsigned short sAl[SPLIT ? 128*40 : 8];
  __shared__ __align__(16) unsigned short sBl[SPLIT ? 128*40 : 8];

  const int tid = threadIdx.x;
  const int lane = tid & 63;
  const int w = tid >> 6;
  const int wr = w >> 1, wc = w & 1;
  const int l16 = lane & 15, lg = lane >> 4;
  const int bm = blockIdx.x, bn = blockIdx.y;

  f32x4 acc[4][4];
  #pragma unroll
  for (int i = 0; i < 4; i++)
    #pragma unroll
    for (int j = 0; j < 4; j++)
      acc[i][j] = (f32x4){0.f,0.f,0.f,0.f};

  for (int kt = 0; kt < K/32; ++kt){
    __syncthreads();
    #pragma unroll
    for (int c = 0; c < 2; c++){
      int lin = tid*16 + c*8;
      int row = lin >> 5, col = lin & 31;
      *(bf16x8*)&sAh[row*40+col] = *(const bf16x8*)&Ah[(size_t)(bm*128+row)*K + kt*32 + col];
      *(bf16x8*)&sBh[row*40+col] = *(const bf16x8*)&Bh[(size_t)(bn*128+row)*K + kt*32 + col];
      if constexpr (SPLIT){
        *(bf16x8*)&sAl[row*40+col] = *(const bf16x8*)&Al[(size_t)(bm*128+row)*K + kt*32 + col];
        *(bf16x8*)&sBl[row*40+col] = *(const bf16x8*)&Bl[(size_t)(bn*128+row)*K + kt*32 + col];
      }
    }
    __syncthreads();

    bf16x8 afh[4], afl[4], bfh[4], bfl[4];
    #pragma unroll
    for (int mi = 0; mi < 4; mi++){
      int off = (wr*64 + mi*16 + l16)*40 + lg*8;
      afh[mi] = *(const bf16x8*)&sAh[off];
      if constexpr (SPLIT) afl[mi] = *(const bf16x8*)&sAl[off];
    }
    #pragma unroll
    for (int ni = 0; ni < 4; ni++){
      int off = (wc*64 + ni*16 + l16)*40 + lg*8;
      bfh[ni] = *(const bf16x8*)&sBh[off];
      if constexpr (SPLIT) bfl[ni] = *(const bf16x8*)&sBl[off];
    }
    #pragma unroll
    for (int mi = 0; mi < 4; mi++)
      #pragma unroll
      for (int ni = 0; ni < 4; ni++){
        acc[mi][ni] = __builtin_amdgcn_mfma_f32_16x16x32_bf16(afh[mi], bfh[ni], acc[mi][ni], 0, 0, 0);
        if constexpr (SPLIT){
          acc[mi][ni] = __builtin_amdgcn_mfma_f32_16x16x32_bf16(afh[mi], bfl[ni], acc[mi][ni], 0, 0, 0);
          acc[mi][ni] = __builtin_amdgcn_mfma_f32_16x16x32_bf16(afl[mi], bfh[ni], acc[mi][ni], 0, 0, 0);
        }
      }
  }

  if constexpr (EPI == 0){
    const int wsel = (bn * 128) >> 10;   // 0=Q,1=K,2=V
    const float* bias = (wsel == 0) ? bias0 : (wsel == 1) ? bias1 : bias2;
    #pragma unroll
    for (int mi = 0; mi < 4; mi++)
      #pragma unroll
      for (int ni = 0; ni < 4; ni++)
        #pragma unroll
        for (int i = 0; i < 4; i++){
          int m = bm*128 + wr*64 + mi*16 + lg*4 + i;
          int ng = bn*128 + wc*64 + ni*16 + l16;
          int n = ng & 1023;
          float v = acc[mi][ni][i] + bias[n];
          int b = m >> 11, s = m & 2047;
          int h = n >> 7, dh = n & 127;
          size_t qidx = ((size_t)(b*8 + h)*2048 + s)*128 + dh;
          if (wsel == 0){
            unsigned short hv = f2bf(v);
            qh[qidx] = hv; ql[qidx] = f2bf(v - bf2f(hv));
          } else if (wsel == 1){
            unsigned short hv = f2bf(v);
            kh[qidx] = hv; kl[qidx] = f2bf(v - bf2f(hv));
          } else {
            vT[((size_t)(b*8 + h)*128 + dh)*2048 + s] = f2bf(v);
          }
        }
  } else {
    #pragma unroll
    for (int mi = 0; mi < 4; mi++)
      #pragma unroll
      for (int ni = 0; ni < 4; ni++)
        #pragma unroll
        for (int i = 0; i < 4; i++){
          int m = bm*128 + wr*64 + mi*16 + lg*4 + i;
          int n = bn*128 + wc*64 + ni*16 + l16;
          outf[(size_t)m*1024 + n] = acc[mi][ni][i] + bias0[n];
        }
  }
}

// ---------------- fused attention v4: swapped QK^T, fused pack+PV (no pd array -> no spill) ----
// One block per (b,h,16-row q-block). 256 threads = 4 waves; wave w owns k-range [512w, 512w+512).
// Score layout (swapped mfma(K,Q)): acc[nt][i] = S[q=l16][k = 512w + 16nt + 4lg + i].
// Peak live regs ~ acc(128, dying 8/t) + pacc(32) + temps -> fits 256-reg cap, zero scratch.
__global__ __launch_bounds__(256, 2) void attn_kernel(
    const unsigned short* __restrict__ qh, const unsigned short* __restrict__ ql,
    const unsigned short* __restrict__ kh, const unsigned short* __restrict__ kl,
    const unsigned short* __restrict__ vT, float* __restrict__ attn_out)
{
  __shared__ __align__(16) float red[4][16][132];     // 33792 B; PV partials
  __shared__ float rpartm[4][16], rpartd[4][16];
  __shared__ unsigned int prefixv[16], kremv[16];
  unsigned int* hist = (unsigned int*)red;            // 2 copies [2][16][257] = 32896 B <= 33792

  const int tid = threadIdx.x;
  const int lane = tid & 63;
  const int w = tid >> 6;
  const int l16 = lane & 15, lg = lane >> 4;
  const int swz = (blockIdx.x & 7) * 256 + (blockIdx.x >> 3);
  const int bh = swz >> 7, qb = swz & 127;
  const float scale = 0.08838834764831845f;           // 128^-0.5

  // Q fragments (hi+lo): B-operand rows q = qb*16 + l16
  const size_t qbase = ((size_t)bh*2048 + qb*16 + l16)*128 + lg*8;
  bf16x8 aqh[4], aql[4];
  #pragma unroll
  for (int kk = 0; kk < 4; kk++){
    aqh[kk] = *(const bf16x8*)&qh[qbase + kk*32];
    aql[kk] = *(const bf16x8*)&ql[qbase + kk*32];
  }

  // scores: A-operand rows k = scol + l16; 2 parallel MFMA chains
  f32x4 acc[32];
  const size_t kbase0 = (size_t)bh*2048*128;
  #pragma unroll
  for (int nt = 0; nt < 32; nt++){
    f32x4 a0 = (f32x4){0.f,0.f,0.f,0.f};
    f32x4 a1 = (f32x4){0.f,0.f,0.f,0.f};
    int scol = (w*32 + nt)*16;
    size_t kb = kbase0 + (size_t)(scol + l16)*128 + lg*8;
    __builtin_amdgcn_s_setprio(1);
    #pragma unroll
    for (int kk = 0; kk < 4; kk++){
      bf16x8 kbh = *(const bf16x8*)&kh[kb + kk*32];
      bf16x8 kbl = *(const bf16x8*)&kl[kb + kk*32];
      a0 = __builtin_amdgcn_mfma_f32_16x16x32_bf16(kbh, aqh[kk], a0, 0, 0, 0);
      a1 = __builtin_amdgcn_mfma_f32_16x16x32_bf16(kbh, aql[kk], a1, 0, 0, 0);
      a1 = __builtin_amdgcn_mfma_f32_16x16x32_bf16(kbl, aqh[kk], a1, 0, 0, 0);
    }
    __builtin_amdgcn_s_setprio(0);
    #pragma unroll
    for (int i = 0; i < 4; i++) acc[nt][i] = (a0[i] + a1[i]) * scale;
  }

  // row max: in-lane + reduce over the 4 lg groups
  {
    float rm = -3.4e38f;
    #pragma unroll
    for (int nt = 0; nt < 32; nt++)
      #pragma unroll
      for (int i = 0; i < 4; i++) rm = fmaxf(rm, acc[nt][i]);
    rm = fmaxf(rm, __shfl_xor(rm, 16, 64));
    rm = fmaxf(rm, __shfl_xor(rm, 32, 64));
    if (lane < 16) rpartm[w][lane] = rm;
  }
  if (tid < 16){ prefixv[tid] = 0u; kremv[tid] = 204u; }   // k = int(2048*0.1)

  // in-place order-preserving radix keys
  #pragma unroll
  for (int nt = 0; nt < 32; nt++)
    #pragma unroll
    for (int i = 0; i < 4; i++)
      acc[nt][i] = __uint_as_float(fkey(acc[nt][i]));

  // parallel radix select: exact k-th largest key per row.
  // 2 hist copies (waves 0-1 / 2-3) -> 8 threads per row-copy on hot buckets.
  const int hco = (w >> 1) * (16*257);
  for (int pass = 3; pass >= 0; pass--){
    const int shift = pass*8;
    __syncthreads();
    for (int j = tid; j < 2*16*257; j += 256) hist[j] = 0u;
    __syncthreads();
    const unsigned int pf = prefixv[l16];
    const unsigned int mhi = (pass == 3) ? 0u : (0xFFFFFFFFu << (shift + 8));
    #pragma unroll
    for (int nt = 0; nt < 32; nt++)
      #pragma unroll
      for (int i = 0; i < 4; i++){
        unsigned int u = __float_as_uint(acc[nt][i]);
        if ((u & mhi) == pf)
          atomicAdd(&hist[hco + l16*257 + ((u >> shift) & 255u)], 1u);
      }
    __syncthreads();
    // wave-parallel bucket scan: wave w handles rows w, w+4, w+8, w+12
    for (int rr = 0; rr < 4; rr++){
      int r = w + rr*4;
      unsigned int krem = kremv[r];
      unsigned int pfx  = prefixv[r];
      unsigned int cl[4], s4 = 0;
      #pragma unroll
      for (int t = 0; t < 4; t++){
        int idx = r*257 + 255 - 4*lane - t;
        cl[t] = hist[idx] + hist[16*257 + idx];
        s4 += cl[t];
      }
      unsigned int inc = s4;
      #pragma unroll
      for (int off = 1; off < 64; off <<= 1){
        unsigned int v = __shfl_up((int)inc, off, 64);
        if (lane >= off) inc += v;
      }
      unsigned int cb = inc - s4;
      #pragma unroll
      for (int t = 0; t < 4; t++){
        if (krem > cb && krem <= cb + cl[t]){
          int d = 255 - 4*lane - t;
          prefixv[r] = pfx | ((unsigned int)d << shift);
          kremv[r]   = krem - cb;
        }
        cb += cl[t];
      }
    }
  }
  __syncthreads();

  // fused: threshold -> exp -> bf16 pack -> lg-exchange -> PV MFMA, one t-step at a time.
  // No pd[16] array: packed fragment consumed immediately (kills the register spill).
  const unsigned int th = prefixv[l16];
  const float rmax = fmaxf(fmaxf(rpartm[0][l16], rpartm[1][l16]),
                           fmaxf(rpartm[2][l16], rpartm[3][l16]));
  const int src01 = ((lg & 1) << 5) + l16;
  const int src23 = src01 + 16;
  const size_t vb0 = (size_t)bh*128*2048 + w*512 + lg*8;
  float dn = 0.f;
  f32x4 pacc[8];
  #pragma unroll
  for (int dt = 0; dt < 8; dt++) pacc[dt] = (f32x4){0.f,0.f,0.f,0.f};
  #pragma unroll
  for (int t = 0; t < 16; t++){
    float p[8];
    #pragma unroll
    for (int j = 0; j < 4; j++){
      unsigned int u = __float_as_uint(acc[2*t][j]);
      p[j] = (u >= th) ? __expf(fkeyinv(u) - rmax) : 0.f;
    }
    #pragma unroll
    for (int j = 0; j < 4; j++){
      unsigned int u = __float_as_uint(acc[2*t+1][j]);
      p[4+j] = (u >= th) ? __expf(fkeyinv(u) - rmax) : 0.f;
    }
    unsigned int d0 = cvtpk(p[0], p[1]), d1 = cvtpk(p[2], p[3]);
    unsigned int d2 = cvtpk(p[4], p[5]), d3 = cvtpk(p[6], p[7]);
    // denominator from the PACKED values (exactly what MFMA consumes)
    dn += __uint_as_float(d0 << 16) + __uint_as_float(d0 & 0xFFFF0000u)
        + __uint_as_float(d1 << 16) + __uint_as_float(d1 & 0xFFFF0000u)
        + __uint_as_float(d2 << 16) + __uint_as_float(d2 & 0xFFFF0000u)
        + __uint_as_float(d3 << 16) + __uint_as_float(d3 & 0xFFFF0000u);
    unsigned int A0 = (unsigned int)__shfl((int)d0, src01, 64);
    unsigned int A1 = (unsigned int)__shfl((int)d1, src01, 64);
    unsigned int A2 = (unsigned int)__shfl((int)d0, src23, 64);
    unsigned int A3 = (unsigned int)__shfl((int)d1, src23, 64);
    unsigned int B0 = (unsigned int)__shfl((int)d2, src01, 64);
    unsigned int B1 = (unsigned int)__shfl((int)d3, src01, 64);
    unsigned int B2 = (unsigned int)__shfl((int)d2, src23, 64);
    unsigned int B3 = (unsigned int)__shfl((int)d3, src23, 64);
    u32x4 pdv = (lg < 2) ? (u32x4){A0, A1, A2, A3} : (u32x4){B0, B1, B2, B3};
    bf16x8 pa = __builtin_bit_cast(bf16x8, pdv);
    __builtin_amdgcn_s_setprio(1);
    #pragma unroll
    for (int dt = 0; dt < 8; dt++){
      bf16x8 bv = *(const bf16x8*)&vT[vb0 + (size_t)(dt*16 + l16)*2048 + t*32];
      pacc[dt] = __builtin_amdgcn_mfma_f32_16x16x32_bf16(pa, bv, pacc[dt], 0, 0, 0);
    }
    __builtin_amdgcn_s_setprio(0);
  }
  dn += __shfl_xor(dn, 16, 64);
  dn += __shfl_xor(dn, 32, 64);
  if (lane < 16) rpartd[w][lane] = dn;

  // partials to LDS: red[w][q][dh] (2-way max conflicts)
  #pragma unroll
  for (int dt = 0; dt < 8; dt++)
    #pragma unroll
    for (int i = 0; i < 4; i++)
      red[w][lg*4 + i][dt*16 + l16] = pacc[dt][i];
  __syncthreads();

  // epilogue: sum 4 wave-partials, divide by denom, store f32
  {
    const int q = tid >> 4;
    const int c0 = (tid & 15) * 8;
    f32x4 s0 = (f32x4){0.f,0.f,0.f,0.f};
    f32x4 s1 = (f32x4){0.f,0.f,0.f,0.f};
    #pragma unroll
    for (int w4 = 0; w4 < 4; w4++){
      s0 += *(const f32x4*)&red[w4][q][c0];
      s1 += *(const f32x4*)&red[w4][q][c0 + 4];
    }
    const float dnm = rpartd[0][q] + rpartd[1][q] + rpartd[2][q] + rpartd[3][q];
    const int b = bh >> 3, h = bh & 7;
    float* op = &attn_out[((size_t)b*2048 + qb*16 + q)*1024 + h*128 + c0];
    f32x4 o0, o1;
    #pragma unroll
    for (int i = 0; i < 4; i++){ o0[i] = s0[i] / dnm; o1[i] = s1[i] / dnm; }
    *(f32x4*)op = o0;
    *(f32x4*)(op + 4) = o1;
  }
}

// ---------------- mean over S, stage 1 ----------------
__global__ void mean_partial_kernel(const float* __restrict__ x, float* __restrict__ partial){
  int b = blockIdx.x >> 5, scn = blockIdx.x & 31;
  int tid = threadIdx.x;
  #pragma unroll
  for (int dc = 0; dc < 4; dc++){
    int d = dc*256 + tid;
    float s = 0.f;
    for (int ss = 0; ss < 64; ss++) s += x[((size_t)b*2048 + scn*64 + ss)*1024 + d];
    partial[((size_t)b*32 + scn)*1024 + d] = s;
  }
}

// ---------------- gate ----------------
__global__ __launch_bounds__(256) void gate_kernel(const float* __restrict__ partial,
    const float* __restrict__ Wg, const float* __restrict__ bg,
    const float* __restrict__ Wgp, const float* __restrict__ bgp,
    float* __restrict__ gate){
  __shared__ float xm[2][1024];
  __shared__ float gb[2][64];
  int tid = threadIdx.x;
  for (int idx = tid; idx < 2048; idx += 256){
    int b = idx >> 10, d = idx & 1023;
    float s = 0.f;
    for (int scn = 0; scn < 32; scn++) s += partial[((size_t)b*32 + scn)*1024 + d];
    xm[b][d] = s * (1.f/2048.f);
  }
  __syncthreads();
  if (tid < 128){
    int b = tid >> 6, j = tid & 63;
    float s = bg[j];
    for (int d = 0; d < 1024; d++) s += xm[b][d] * Wg[j*1024 + d];
    gb[b][j] = 1.f / (1.f + __expf(-s));
  }
  __syncthreads();
  for (int idx = tid; idx < 2048; idx += 256){
    int b = idx >> 10, d = idx & 1023;
    float s = bgp[d];
    for (int j = 0; j < 64; j++) s += gb[b][j] * Wgp[d*64 + j];
    gate[idx] = s;
  }
}

// ---------------- distill + mix, write mixed as split bf16 (hi+lo) ----------------
__global__ __launch_bounds__(256) void mix_kernel(const float* __restrict__ attn,
    const float* __restrict__ Wd, const float* __restrict__ bd,
    const float* __restrict__ gate,
    unsigned short* __restrict__ mixedh, unsigned short* __restrict__ mixedl){
  __shared__ float sWdT[64*64];
  __shared__ float arow[1024];
  int tid = threadIdx.x;
  for (int i = tid; i < 4096; i += 256){
    int m = i >> 6, cc = i & 63;
    sWdT[i] = Wd[cc*64 + m];
  }
  int rbase = blockIdx.x * 16;
  for (int rr = 0; rr < 16; rr++){
    int row = rbase + rr;
    __syncthreads();
    for (int i = tid; i < 1024; i += 256) arow[i] = attn[(size_t)row*1024 + i];
    __syncthreads();
    int b = row >> 11;
    #pragma unroll
    for (int c4 = 0; c4 < 4; c4++){
      int dcol = c4*256 + tid;
      int j = dcol >> 6, cc = dcol & 63;
      float y = bd[cc];
      for (int m = 0; m < 64; m++) y += arow[j*64 + m] * sWdT[m*64 + cc];
      float g = gate[b*1024 + dcol];
      float mv = g*y + (1.f - g)*arow[dcol];
      unsigned short hv = f2bf(mv);
      mixedh[(size_t)row*1024 + dcol] = hv;
      mixedl[(size_t)row*1024 + dcol] = f2bf(mv - bf2f(hv));
    }
  }
}

// ---------------- launch ----------------
// Workspace layout (total 68 MiB; replay-proven safe):
//   [ 0, 8)  MiB xh      (dead after QKV gemm)   } attnws [0,16) aliases both
//   [ 8,16)  MiB xl      (dead after QKV gemm)   }
//   [16,22)  MiB whi     (dead after QKV gemm)   } wohi [16,18), wolo [18,20),
//   [22,28)  MiB wlo     (dead after QKV gemm)   } partial [20,+256K), gatews next — all after QKV
//   [28,36)  MiB qh  -> mixedh after attn
//   [36,44)  MiB ql  -> mixedl after attn
//   [44,52)  MiB kh
//   [52,60)  MiB kl
//   [60,68)  MiB vT
extern "C" void kernel_launch(void* const* d_in, const int* in_sizes, int n_in,
                              void* d_out, int out_size, void* d_ws, size_t ws_size,
                              hipStream_t stream){
  (void)in_sizes; (void)n_in; (void)out_size; (void)ws_size;
  const float* x   = (const float*)d_in[0];
  const float* Wq  = (const float*)d_in[1];
  const float* bq  = (const float*)d_in[2];
  const float* Wk  = (const float*)d_in[3];
  const float* bk  = (const float*)d_in[4];
  const float* Wv  = (const float*)d_in[5];
  const float* bv  = (const float*)d_in[6];
  const float* Wo  = (const float*)d_in[7];
  const float* bo  = (const float*)d_in[8];
  const float* Wd  = (const float*)d_in[9];
  const float* bd  = (const float*)d_in[10];
  const float* Wg  = (const float*)d_in[11];
  const float* bg  = (const float*)d_in[12];
  const float* Wgp = (const float*)d_in[13];
  const float* bgp = (const float*)d_in[14];
  float* out = (float*)d_out;

  const size_t MiB = 1048576;
  char* ws = (char*)d_ws;
  unsigned short* xh     = (unsigned short*)(ws + 0*MiB);
  unsigned short* xl     = (unsigned short*)(ws + 8*MiB);
  float*          attnws = (float*)(ws + 0*MiB);            // aliases xh/xl after QKV
  unsigned short* whi    = (unsigned short*)(ws + 16*MiB);  // [3072,1024]
  unsigned short* wlo    = (unsigned short*)(ws + 22*MiB);
  unsigned short* wohi   = (unsigned short*)(ws + 16*MiB);  // aliases whi, written after QKV
  unsigned short* wolo   = (unsigned short*)(ws + 18*MiB);
  float*          partial= (float*)(ws + 20*MiB);           // 256 KiB, within dead whi
  float*          gatews = (float*)(ws + 20*MiB + 262144);  // 8 KiB
  unsigned short* qh_    = (unsigned short*)(ws + 28*MiB);
  unsigned short* ql_    = (unsigned short*)(ws + 36*MiB);
  unsigned short* mixedh = (unsigned short*)(ws + 28*MiB);  // aliases qh after attn
  unsigned short* mixedl = (unsigned short*)(ws + 36*MiB);  // aliases ql after attn
  unsigned short* kh_    = (unsigned short*)(ws + 44*MiB);
  unsigned short* kl_    = (unsigned short*)(ws + 52*MiB);
  unsigned short* vT_    = (unsigned short*)(ws + 60*MiB);  // ends at 68 MiB

  prep_split_kernel<<<16384, 256, 0, stream>>>(x,  xh, xl, 4194304);
  prep_split_kernel<<<4096,  256, 0, stream>>>(Wq, whi,           wlo,           1048576);
  prep_split_kernel<<<4096,  256, 0, stream>>>(Wk, whi + 1048576, wlo + 1048576, 1048576);
  prep_split_kernel<<<4096,  256, 0, stream>>>(Wv, whi + 2097152, wlo + 2097152, 1048576);

  gemm_kernel<true, 0><<<dim3(32, 24), 256, 0, stream>>>(
      xh, xl, whi, wlo, bq, bk, bv, qh_, ql_, kh_, kl_, vT_, nullptr);

  // Wo split written AFTER the QKV gemm (wohi/wolo alias the then-dead whi region)
  prep_split_kernel<<<4096,  256, 0, stream>>>(Wo, wohi, wolo, 1048576);

  attn_kernel<<<2048, 256, 0, stream>>>(qh_, ql_, kh_, kl_, vT_, attnws);

  mean_partial_kernel<<<64, 256, 0, stream>>>(x, partial);
  gate_kernel<<<1, 256, 0, stream>>>(partial, Wg, bg, Wgp, bgp, gatews);

  mix_kernel<<<256, 256, 0, stream>>>(attnws, Wd, bd, gatews, mixedh, mixedl);

  gemm_kernel<true, 1><<<dim3(32, 8), 256, 0, stream>>>(
      mixedh, mixedl, wohi, wolo, bo, nullptr, nullptr,
      nullptr, nullptr, nullptr, nullptr, nullptr, out);
}

// Round 6
// 684.044 us; speedup vs baseline: 1.1053x; 1.1053x over previous
//
#include <hip/hip_runtime.h>

typedef __attribute__((ext_vector_type(8))) short bf16x8;
typedef __attribute__((ext_vector_type(4))) float f32x4;
typedef __attribute__((ext_vector_type(4))) unsigned int u32x4;

#define DEVINL __device__ __forceinline__

DEVINL unsigned short f2bf(float f){
  unsigned int u = __float_as_uint(f);
  unsigned int r = (u + 0x7FFFu + ((u >> 16) & 1u)) >> 16;
  return (unsigned short)r;
}
DEVINL float bf2f(unsigned short h){ return __uint_as_float(((unsigned int)h) << 16); }
DEVINL unsigned int fkey(float f){
  unsigned int u = __float_as_uint(f);
  return (u & 0x80000000u) ? ~u : (u | 0x80000000u);
}
DEVINL float fkeyinv(unsigned int k){
  unsigned int u = (k & 0x80000000u) ? (k & 0x7FFFFFFFu) : ~k;
  return __uint_as_float(u);
}
DEVINL unsigned int cvtpk(float lo, float hi){
  unsigned int r;
  asm("v_cvt_pk_bf16_f32 %0, %1, %2" : "=v"(r) : "v"(lo), "v"(hi));
  return r;
}

// ---------------- prep: f32 -> bf16 hi (+ optional lo residual) ----------------
__global__ void prep_split_kernel(const float* __restrict__ src,
                                  unsigned short* __restrict__ hi,
                                  unsigned short* __restrict__ lo, int n){
  int i = blockIdx.x * 256 + threadIdx.x;
  if (i >= n) return;
  float f = src[i];
  unsigned short h = f2bf(f);
  hi[i] = h;
  if (lo) lo[i] = f2bf(f - bf2f(h));
}

// ---------------- GEMM: C[m,n] = sum_k A[m,k]*B[n,k] + bias, 128x128 tile ----------------
template<bool SPLIT, int EPI>
__global__ __launch_bounds__(256) void gemm_kernel(
    const unsigned short* __restrict__ Ah, const unsigned short* __restrict__ Al,
    const unsigned short* __restrict__ Bh, const unsigned short* __restrict__ Bl,
    const float* __restrict__ bias0, const float* __restrict__ bias1, const float* __restrict__ bias2,
    unsigned short* __restrict__ qh, unsigned short* __restrict__ ql,
    unsigned short* __restrict__ kh, unsigned short* __restrict__ kl,
    unsigned short* __restrict__ vT, float* __restrict__ outf)
{
  const int K = 1024;
  __shared__ __align__(16) unsigned short sAh[128*40];
  __shared__ __align__(16) unsigned short sBh[128*40];
  __shared__ __align__(16) unsigned short sAl[SPLIT ? 128*40 : 8];
  __shared__ __align__(16) unsigned short sBl[SPLIT ? 128*40 : 8];

  const int tid = threadIdx.x;
  const int lane = tid & 63;
  const int w = tid >> 6;
  const int wr = w >> 1, wc = w & 1;
  const int l16 = lane & 15, lg = lane >> 4;
  const int bm = blockIdx.x, bn = blockIdx.y;

  f32x4 acc[4][4];
  #pragma unroll
  for (int i = 0; i < 4; i++)
    #pragma unroll
    for (int j = 0; j < 4; j++)
      acc[i][j] = (f32x4){0.f,0.f,0.f,0.f};

  for (int kt = 0; kt < K/32; ++kt){
    __syncthreads();
    #pragma unroll
    for (int c = 0; c < 2; c++){
      int lin = tid*16 + c*8;
      int row = lin >> 5, col = lin & 31;
      *(bf16x8*)&sAh[row*40+col] = *(const bf16x8*)&Ah[(size_t)(bm*128+row)*K + kt*32 + col];
      *(bf16x8*)&sBh[row*40+col] = *(const bf16x8*)&Bh[(size_t)(bn*128+row)*K + kt*32 + col];
      if constexpr (SPLIT){
        *(bf16x8*)&sAl[row*40+col] = *(const bf16x8*)&Al[(size_t)(bm*128+row)*K + kt*32 + col];
        *(bf16x8*)&sBl[row*40+col] = *(const bf16x8*)&Bl[(size_t)(bn*128+row)*K + kt*32 + col];
      }
    }
    __syncthreads();

    bf16x8 afh[4], afl[4], bfh[4], bfl[4];
    #pragma unroll
    for (int mi = 0; mi < 4; mi++){
      int off = (wr*64 + mi*16 + l16)*40 + lg*8;
      afh[mi] = *(const bf16x8*)&sAh[off];
      if constexpr (SPLIT) afl[mi] = *(const bf16x8*)&sAl[off];
    }
    #pragma unroll
    for (int ni = 0; ni < 4; ni++){
      int off = (wc*64 + ni*16 + l16)*40 + lg*8;
      bfh[ni] = *(const bf16x8*)&sBh[off];
      if constexpr (SPLIT) bfl[ni] = *(const bf16x8*)&sBl[off];
    }
    #pragma unroll
    for (int mi = 0; mi < 4; mi++)
      #pragma unroll
      for (int ni = 0; ni < 4; ni++){
        acc[mi][ni] = __builtin_amdgcn_mfma_f32_16x16x32_bf16(afh[mi], bfh[ni], acc[mi][ni], 0, 0, 0);
        if constexpr (SPLIT){
          acc[mi][ni] = __builtin_amdgcn_mfma_f32_16x16x32_bf16(afh[mi], bfl[ni], acc[mi][ni], 0, 0, 0);
          acc[mi][ni] = __builtin_amdgcn_mfma_f32_16x16x32_bf16(afl[mi], bfh[ni], acc[mi][ni], 0, 0, 0);
        }
      }
  }

  if constexpr (EPI == 0){
    const int wsel = (bn * 128) >> 10;   // 0=Q,1=K,2=V
    const float* bias = (wsel == 0) ? bias0 : (wsel == 1) ? bias1 : bias2;
    #pragma unroll
    for (int mi = 0; mi < 4; mi++)
      #pragma unroll
      for (int ni = 0; ni < 4; ni++)
        #pragma unroll
        for (int i = 0; i < 4; i++){
          int m = bm*128 + wr*64 + mi*16 + lg*4 + i;
          int ng = bn*128 + wc*64 + ni*16 + l16;
          int n = ng & 1023;
          float v = acc[mi][ni][i] + bias[n];
          int b = m >> 11, s = m & 2047;
          int h = n >> 7, dh = n & 127;
          size_t qidx = ((size_t)(b*8 + h)*2048 + s)*128 + dh;
          if (wsel == 0){
            unsigned short hv = f2bf(v);
            qh[qidx] = hv; ql[qidx] = f2bf(v - bf2f(hv));
          } else if (wsel == 1){
            unsigned short hv = f2bf(v);
            kh[qidx] = hv; kl[qidx] = f2bf(v - bf2f(hv));
          } else {
            vT[((size_t)(b*8 + h)*128 + dh)*2048 + s] = f2bf(v);
          }
        }
  } else {
    #pragma unroll
    for (int mi = 0; mi < 4; mi++)
      #pragma unroll
      for (int ni = 0; ni < 4; ni++)
        #pragma unroll
        for (int i = 0; i < 4; i++){
          int m = bm*128 + wr*64 + mi*16 + lg*4 + i;
          int n = bn*128 + wc*64 + ni*16 + l16;
          outf[(size_t)m*1024 + n] = acc[mi][ni][i] + bias0[n];
        }
  }
}

// ---------------- fused attention v5: 8 waves/block, 64 scores/thread -> no spill ----------------
// One block per (b,h,16-row q-block). 512 threads = 8 waves; wave w owns k-range [256w, 256w+256).
// Score layout (swapped mfma(K,Q)): acc[nt][i] = S[q=l16][k = 256w + 16nt + 4lg + i].
// Peak live regs ~ acc(64) + pacc(32) + temps ~ 116 < 128 cap -> zero scratch.
__global__ __launch_bounds__(512, 4) void attn_kernel(
    const unsigned short* __restrict__ qh, const unsigned short* __restrict__ ql,
    const unsigned short* __restrict__ kh, const unsigned short* __restrict__ kl,
    const unsigned short* __restrict__ vT, float* __restrict__ attn_out)
{
  __shared__ __align__(16) float red[8][16][132];     // 67584 B; PV partials
  __shared__ float rpartm[8][16], rpartd[8][16];
  __shared__ unsigned int prefixv[16], kremv[16];
  unsigned int* hist = (unsigned int*)red;            // 4 copies [4][16][257] = 65792 B <= 67584

  const int tid = threadIdx.x;
  const int lane = tid & 63;
  const int w = tid >> 6;                             // 0..7
  const int l16 = lane & 15, lg = lane >> 4;
  const int swz = (blockIdx.x & 7) * 256 + (blockIdx.x >> 3);
  const int bh = swz >> 7, qb = swz & 127;
  const float scale = 0.08838834764831845f;           // 128^-0.5

  // Q fragments (hi+lo): B-operand rows q = qb*16 + l16
  const size_t qbase = ((size_t)bh*2048 + qb*16 + l16)*128 + lg*8;
  bf16x8 aqh[4], aql[4];
  #pragma unroll
  for (int kk = 0; kk < 4; kk++){
    aqh[kk] = *(const bf16x8*)&qh[qbase + kk*32];
    aql[kk] = *(const bf16x8*)&ql[qbase + kk*32];
  }

  // scores: A-operand rows k = scol + l16; 2 parallel MFMA chains
  f32x4 acc[16];
  const size_t kbase0 = (size_t)bh*2048*128;
  #pragma unroll
  for (int nt = 0; nt < 16; nt++){
    f32x4 a0 = (f32x4){0.f,0.f,0.f,0.f};
    f32x4 a1 = (f32x4){0.f,0.f,0.f,0.f};
    int scol = (w*16 + nt)*16;
    size_t kb = kbase0 + (size_t)(scol + l16)*128 + lg*8;
    __builtin_amdgcn_s_setprio(1);
    #pragma unroll
    for (int kk = 0; kk < 4; kk++){
      bf16x8 kbh = *(const bf16x8*)&kh[kb + kk*32];
      bf16x8 kbl = *(const bf16x8*)&kl[kb + kk*32];
      a0 = __builtin_amdgcn_mfma_f32_16x16x32_bf16(kbh, aqh[kk], a0, 0, 0, 0);
      a1 = __builtin_amdgcn_mfma_f32_16x16x32_bf16(kbh, aql[kk], a1, 0, 0, 0);
      a1 = __builtin_amdgcn_mfma_f32_16x16x32_bf16(kbl, aqh[kk], a1, 0, 0, 0);
    }
    __builtin_amdgcn_s_setprio(0);
    #pragma unroll
    for (int i = 0; i < 4; i++) acc[nt][i] = (a0[i] + a1[i]) * scale;
  }

  // row max: in-lane + reduce over the 4 lg groups; 8 wave-partials in LDS
  {
    float rm = -3.4e38f;
    #pragma unroll
    for (int nt = 0; nt < 16; nt++)
      #pragma unroll
      for (int i = 0; i < 4; i++) rm = fmaxf(rm, acc[nt][i]);
    rm = fmaxf(rm, __shfl_xor(rm, 16, 64));
    rm = fmaxf(rm, __shfl_xor(rm, 32, 64));
    if (lane < 16) rpartm[w][lane] = rm;
  }
  if (tid < 16){ prefixv[tid] = 0u; kremv[tid] = 204u; }   // k = int(2048*0.1)

  // in-place order-preserving radix keys
  #pragma unroll
  for (int nt = 0; nt < 16; nt++)
    #pragma unroll
    for (int i = 0; i < 4; i++)
      acc[nt][i] = __uint_as_float(fkey(acc[nt][i]));

  // parallel radix select: exact k-th largest key per row.
  // 4 hist copies (2 waves each) -> 8 threads per row-copy on hot buckets.
  const int hco = (w >> 1) * (16*257);
  for (int pass = 3; pass >= 0; pass--){
    const int shift = pass*8;
    __syncthreads();
    for (int j = tid; j < 4*16*257; j += 512) hist[j] = 0u;
    __syncthreads();
    const unsigned int pf = prefixv[l16];
    const unsigned int mhi = (pass == 3) ? 0u : (0xFFFFFFFFu << (shift + 8));
    #pragma unroll
    for (int nt = 0; nt < 16; nt++)
      #pragma unroll
      for (int i = 0; i < 4; i++){
        unsigned int u = __float_as_uint(acc[nt][i]);
        if ((u & mhi) == pf)
          atomicAdd(&hist[hco + l16*257 + ((u >> shift) & 255u)], 1u);
      }
    __syncthreads();
    // wave-parallel bucket scan: wave w handles rows 2w, 2w+1
    #pragma unroll
    for (int rr = 0; rr < 2; rr++){
      int r = w*2 + rr;
      unsigned int krem = kremv[r];
      unsigned int pfx  = prefixv[r];
      unsigned int cl[4], s4 = 0;
      #pragma unroll
      for (int t = 0; t < 4; t++){
        int idx = r*257 + 255 - 4*lane - t;
        cl[t] = hist[idx] + hist[16*257 + idx] + hist[2*16*257 + idx] + hist[3*16*257 + idx];
        s4 += cl[t];
      }
      unsigned int inc = s4;
      #pragma unroll
      for (int off = 1; off < 64; off <<= 1){
        unsigned int v = __shfl_up((int)inc, off, 64);
        if (lane >= off) inc += v;
      }
      unsigned int cb = inc - s4;
      #pragma unroll
      for (int t = 0; t < 4; t++){
        if (krem > cb && krem <= cb + cl[t]){
          int d = 255 - 4*lane - t;
          prefixv[r] = pfx | ((unsigned int)d << shift);
          kremv[r]   = krem - cb;
        }
        cb += cl[t];
      }
    }
  }
  __syncthreads();

  // fused: threshold -> exp -> bf16 pack -> lg-exchange -> PV MFMA, one 32-k step at a time
  const unsigned int th = prefixv[l16];
  float rmax = rpartm[0][l16];
  #pragma unroll
  for (int w8 = 1; w8 < 8; w8++) rmax = fmaxf(rmax, rpartm[w8][l16]);
  const int src01 = ((lg & 1) << 5) + l16;
  const int src23 = src01 + 16;
  const size_t vb0 = (size_t)bh*128*2048 + w*256 + lg*8;
  float dn = 0.f;
  f32x4 pacc[8];
  #pragma unroll
  for (int dt = 0; dt < 8; dt++) pacc[dt] = (f32x4){0.f,0.f,0.f,0.f};
  #pragma unroll
  for (int t = 0; t < 8; t++){
    float p[8];
    #pragma unroll
    for (int j = 0; j < 4; j++){
      unsigned int u = __float_as_uint(acc[2*t][j]);
      p[j] = (u >= th) ? __expf(fkeyinv(u) - rmax) : 0.f;
    }
    #pragma unroll
    for (int j = 0; j < 4; j++){
      unsigned int u = __float_as_uint(acc[2*t+1][j]);
      p[4+j] = (u >= th) ? __expf(fkeyinv(u) - rmax) : 0.f;
    }
    unsigned int d0 = cvtpk(p[0], p[1]), d1 = cvtpk(p[2], p[3]);
    unsigned int d2 = cvtpk(p[4], p[5]), d3 = cvtpk(p[6], p[7]);
    // denominator from the PACKED values (exactly what MFMA consumes)
    dn += __uint_as_float(d0 << 16) + __uint_as_float(d0 & 0xFFFF0000u)
        + __uint_as_float(d1 << 16) + __uint_as_float(d1 & 0xFFFF0000u)
        + __uint_as_float(d2 << 16) + __uint_as_float(d2 & 0xFFFF0000u)
        + __uint_as_float(d3 << 16) + __uint_as_float(d3 & 0xFFFF0000u);
    unsigned int A0 = (unsigned int)__shfl((int)d0, src01, 64);
    unsigned int A1 = (unsigned int)__shfl((int)d1, src01, 64);
    unsigned int A2 = (unsigned int)__shfl((int)d0, src23, 64);
    unsigned int A3 = (unsigned int)__shfl((int)d1, src23, 64);
    unsigned int B0 = (unsigned int)__shfl((int)d2, src01, 64);
    unsigned int B1 = (unsigned int)__shfl((int)d3, src01, 64);
    unsigned int B2 = (unsigned int)__shfl((int)d2, src23, 64);
    unsigned int B3 = (unsigned int)__shfl((int)d3, src23, 64);
    u32x4 pdv = (lg < 2) ? (u32x4){A0, A1, A2, A3} : (u32x4){B0, B1, B2, B3};
    bf16x8 pa = __builtin_bit_cast(bf16x8, pdv);
    __builtin_amdgcn_s_setprio(1);
    #pragma unroll
    for (int dt = 0; dt < 8; dt++){
      bf16x8 bv = *(const bf16x8*)&vT[vb0 + (size_t)(dt*16 + l16)*2048 + t*32];
      pacc[dt] = __builtin_amdgcn_mfma_f32_16x16x32_bf16(pa, bv, pacc[dt], 0, 0, 0);
    }
    __builtin_amdgcn_s_setprio(0);
  }
  dn += __shfl_xor(dn, 16, 64);
  dn += __shfl_xor(dn, 32, 64);
  if (lane < 16) rpartd[w][lane] = dn;

  // partials to LDS: red[w][q][dh]
  #pragma unroll
  for (int dt = 0; dt < 8; dt++)
    #pragma unroll
    for (int i = 0; i < 4; i++)
      red[w][lg*4 + i][dt*16 + l16] = pacc[dt][i];
  __syncthreads();

  // epilogue: sum 8 wave-partials, divide by denom, store f32 (coalesced 512B/q-row)
  {
    const int q = tid >> 5;
    const int c0 = (tid & 31) * 4;
    f32x4 s0 = (f32x4){0.f,0.f,0.f,0.f};
    #pragma unroll
    for (int w8 = 0; w8 < 8; w8++)
      s0 += *(const f32x4*)&red[w8][q][c0];
    float dnm = 0.f;
    #pragma unroll
    for (int w8 = 0; w8 < 8; w8++) dnm += rpartd[w8][q];
    const int b = bh >> 3, h = bh & 7;
    float* op = &attn_out[((size_t)b*2048 + qb*16 + q)*1024 + h*128 + c0];
    f32x4 o0;
    #pragma unroll
    for (int i = 0; i < 4; i++) o0[i] = s0[i] / dnm;
    *(f32x4*)op = o0;
  }
}

// ---------------- mean over S, stage 1 ----------------
__global__ void mean_partial_kernel(const float* __restrict__ x, float* __restrict__ partial){
  int b = blockIdx.x >> 5, scn = blockIdx.x & 31;
  int tid = threadIdx.x;
  #pragma unroll
  for (int dc = 0; dc < 4; dc++){
    int d = dc*256 + tid;
    float s = 0.f;
    for (int ss = 0; ss < 64; ss++) s += x[((size_t)b*2048 + scn*64 + ss)*1024 + d];
    partial[((size_t)b*32 + scn)*1024 + d] = s;
  }
}

// ---------------- gate ----------------
__global__ __launch_bounds__(256) void gate_kernel(const float* __restrict__ partial,
    const float* __restrict__ Wg, const float* __restrict__ bg,
    const float* __restrict__ Wgp, const float* __restrict__ bgp,
    float* __restrict__ gate){
  __shared__ float xm[2][1024];
  __shared__ float gb[2][64];
  int tid = threadIdx.x;
  for (int idx = tid; idx < 2048; idx += 256){
    int b = idx >> 10, d = idx & 1023;
    float s = 0.f;
    for (int scn = 0; scn < 32; scn++) s += partial[((size_t)b*32 + scn)*1024 + d];
    xm[b][d] = s * (1.f/2048.f);
  }
  __syncthreads();
  if (tid < 128){
    int b = tid >> 6, j = tid & 63;
    float s = bg[j];
    for (int d = 0; d < 1024; d++) s += xm[b][d] * Wg[j*1024 + d];
    gb[b][j] = 1.f / (1.f + __expf(-s));
  }
  __syncthreads();
  for (int idx = tid; idx < 2048; idx += 256){
    int b = idx >> 10, d = idx & 1023;
    float s = bgp[d];
    for (int j = 0; j < 64; j++) s += gb[b][j] * Wgp[d*64 + j];
    gate[idx] = s;
  }
}

// ---------------- distill + mix, write mixed as split bf16 (hi+lo) ----------------
__global__ __launch_bounds__(256) void mix_kernel(const float* __restrict__ attn,
    const float* __restrict__ Wd, const float* __restrict__ bd,
    const float* __restrict__ gate,
    unsigned short* __restrict__ mixedh, unsigned short* __restrict__ mixedl){
  __shared__ float sWdT[64*64];
  __shared__ float arow[1024];
  int tid = threadIdx.x;
  for (int i = tid; i < 4096; i += 256){
    int m = i >> 6, cc = i & 63;
    sWdT[i] = Wd[cc*64 + m];
  }
  int rbase = blockIdx.x * 16;
  for (int rr = 0; rr < 16; rr++){
    int row = rbase + rr;
    __syncthreads();
    for (int i = tid; i < 1024; i += 256) arow[i] = attn[(size_t)row*1024 + i];
    __syncthreads();
    int b = row >> 11;
    #pragma unroll
    for (int c4 = 0; c4 < 4; c4++){
      int dcol = c4*256 + tid;
      int j = dcol >> 6, cc = dcol & 63;
      float y = bd[cc];
      for (int m = 0; m < 64; m++) y += arow[j*64 + m] * sWdT[m*64 + cc];
      float g = gate[b*1024 + dcol];
      float mv = g*y + (1.f - g)*arow[dcol];
      unsigned short hv = f2bf(mv);
      mixedh[(size_t)row*1024 + dcol] = hv;
      mixedl[(size_t)row*1024 + dcol] = f2bf(mv - bf2f(hv));
    }
  }
}

// ---------------- launch ----------------
// Workspace layout (total 68 MiB; replay-proven safe):
//   [ 0, 8)  MiB xh      (dead after QKV gemm)   } attnws [0,16) aliases both
//   [ 8,16)  MiB xl      (dead after QKV gemm)   }
//   [16,22)  MiB whi     (dead after QKV gemm)   } wohi [16,18), wolo [18,20),
//   [22,28)  MiB wlo     (dead after QKV gemm)   } partial [20,+256K), gatews next — all after QKV
//   [28,36)  MiB qh  -> mixedh after attn
//   [36,44)  MiB ql  -> mixedl after attn
//   [44,52)  MiB kh
//   [52,60)  MiB kl
//   [60,68)  MiB vT
extern "C" void kernel_launch(void* const* d_in, const int* in_sizes, int n_in,
                              void* d_out, int out_size, void* d_ws, size_t ws_size,
                              hipStream_t stream){
  (void)in_sizes; (void)n_in; (void)out_size; (void)ws_size;
  const float* x   = (const float*)d_in[0];
  const float* Wq  = (const float*)d_in[1];
  const float* bq  = (const float*)d_in[2];
  const float* Wk  = (const float*)d_in[3];
  const float* bk  = (const float*)d_in[4];
  const float* Wv  = (const float*)d_in[5];
  const float* bv  = (const float*)d_in[6];
  const float* Wo  = (const float*)d_in[7];
  const float* bo  = (const float*)d_in[8];
  const float* Wd  = (const float*)d_in[9];
  const float* bd  = (const float*)d_in[10];
  const float* Wg  = (const float*)d_in[11];
  const float* bg  = (const float*)d_in[12];
  const float* Wgp = (const float*)d_in[13];
  const float* bgp = (const float*)d_in[14];
  float* out = (float*)d_out;

  const size_t MiB = 1048576;
  char* ws = (char*)d_ws;
  unsigned short* xh     = (unsigned short*)(ws + 0*MiB);
  unsigned short* xl     = (unsigned short*)(ws + 8*MiB);
  float*          attnws = (float*)(ws + 0*MiB);            // aliases xh/xl after QKV
  unsigned short* whi    = (unsigned short*)(ws + 16*MiB);  // [3072,1024]
  unsigned short* wlo    = (unsigned short*)(ws + 22*MiB);
  unsigned short* wohi   = (unsigned short*)(ws + 16*MiB);  // aliases whi, written after QKV
  unsigned short* wolo   = (unsigned short*)(ws + 18*MiB);
  float*          partial= (float*)(ws + 20*MiB);           // 256 KiB, within dead whi
  float*          gatews = (float*)(ws + 20*MiB + 262144);  // 8 KiB
  unsigned short* qh_    = (unsigned short*)(ws + 28*MiB);
  unsigned short* ql_    = (unsigned short*)(ws + 36*MiB);
  unsigned short* mixedh = (unsigned short*)(ws + 28*MiB);  // aliases qh after attn
  unsigned short* mixedl = (unsigned short*)(ws + 36*MiB);  // aliases ql after attn
  unsigned short* kh_    = (unsigned short*)(ws + 44*MiB);
  unsigned short* kl_    = (unsigned short*)(ws + 52*MiB);
  unsigned short* vT_    = (unsigned short*)(ws + 60*MiB);  // ends at 68 MiB

  prep_split_kernel<<<16384, 256, 0, stream>>>(x,  xh, xl, 4194304);
  prep_split_kernel<<<4096,  256, 0, stream>>>(Wq, whi,           wlo,           1048576);
  prep_split_kernel<<<4096,  256, 0, stream>>>(Wk, whi + 1048576, wlo + 1048576, 1048576);
  prep_split_kernel<<<4096,  256, 0, stream>>>(Wv, whi + 2097152, wlo + 2097152, 1048576);

  gemm_kernel<true, 0><<<dim3(32, 24), 256, 0, stream>>>(
      xh, xl, whi, wlo, bq, bk, bv, qh_, ql_, kh_, kl_, vT_, nullptr);

  // Wo split written AFTER the QKV gemm (wohi/wolo alias the then-dead whi region)
  prep_split_kernel<<<4096,  256, 0, stream>>>(Wo, wohi, wolo, 1048576);

  attn_kernel<<<2048, 512, 0, stream>>>(qh_, ql_, kh_, kl_, vT_, attnws);

  mean_partial_kernel<<<64, 256, 0, stream>>>(x, partial);
  gate_kernel<<<1, 256, 0, stream>>>(partial, Wg, bg, Wgp, bgp, gatews);

  mix_kernel<<<256, 256, 0, stream>>>(attnws, Wd, bd, gatews, mixedh, mixedl);

  gemm_kernel<true, 1><<<dim3(32, 8), 256, 0, stream>>>(
      mixedh, mixedl, wohi, wolo, bo, nullptr, nullptr,
      nullptr, nullptr, nullptr, nullptr, nullptr, out);
}